// Round 3
// baseline (247.518 us; speedup 1.0000x reference)
//
#include <hip/hip_runtime.h>
#include <cstdint>
#include <cstddef>

// x[B=32, T=4096, N=256] fp32 -> z same shape.
// Refractory scan: spike at step t iff x>0 and t >= na; then na = t+6.
// Entry state q==k <=> first k steps of chunk blocked. q in [0,5].
//
// R3 == R2 design (CC=16, grid 512, decoupled lookback) with hardening:
//  - dropped t16[] register cache in phase 2 (read tbl_lds directly) to
//    keep VGPR comfortably under the 64-reg budget of launch_bounds(1024,8)
//  - R2's failure had no timing/compile/validation data => harness/container
//    level; protocol re-audited: publish never waits, residency = grid.
#define BB 32
#define TT 4096
#define NNV 64        // float4 groups per row (N=256)
#define CC 16         // chunk length (per-thread scan)
#define PSUB 16       // chunks per block (one per 64-lane wave)
#define PG 16         // chunk-groups per chain: T / (CC*PSUB)
#define NCH 256       // chains (N)

__global__ __launch_bounds__(1024, 8) void refrac_fused(const float* __restrict__ x,
                                                        float* __restrict__ z,
                                                        uint32_t* __restrict__ msg) {
    const int tid = threadIdx.x;
    const int pg = blockIdx.x >> 5;   // chunk-group; lower pg = lower blockIdx
    const int b  = blockIdx.x & 31;   // batch
    const int psub = tid >> 6;        // which of the 16 chunks (== wave id)
    const int n4 = tid & 63;          // float4 group along N
    const int p = pg * PSUB + psub;   // absolute chunk index

    const float4* __restrict__ xv = reinterpret_cast<const float4*>(x)
        + ((size_t)b * TT + (size_t)p * CC) * NNV + n4;

    // --- Phase 1: pure load + sign-bit extraction (16 steps) ---
    uint32_t cur[4] = {0u, 0u, 0u, 0u};
    #pragma unroll
    for (int jb = 0; jb < CC; jb += 8) {
        float4 buf[8];
        #pragma unroll
        for (int u = 0; u < 8; ++u)
            buf[u] = xv[(size_t)(jb + u) * NNV];
        #pragma unroll
        for (int u = 0; u < 8; ++u) {
            const int j = jb + u;
            const float fv[4] = {buf[u].x, buf[u].y, buf[u].z, buf[u].w};
            #pragma unroll
            for (int c = 0; c < 4; ++c)
                cur[c] |= (fv[c] > 0.0f) ? (1u << j) : 0u;
        }
    }

    // --- Per-chunk 6-entry exit tables via bitmask walk ---
    // A spike advances na by 6, so a 16-step chunk has <=3 spikes: 3 fixed
    // branchless iterations. Sentinel bit16 makes ctz safe when no spike.
    __shared__ uint32_t tbl_lds[PSUB][NCH];  // 16 KB: 6 nibbles per chain
    __shared__ uint8_t  ent_lds[PSUB][NCH];  //  4 KB: resolved entry states

    #pragma unroll
    for (int c = 0; c < 4; ++c) {
        const uint32_t m = cur[c];
        uint32_t tbl = 0;
        #pragma unroll
        for (int e = 0; e < 6; ++e) {
            int na = e;
            #pragma unroll
            for (int it = 0; it < 3; ++it) {
                const uint32_t r = m >> (na & 31);   // na <= 21 always
                const int t = na + __builtin_ctz(r | 0x10000u);
                na = r ? (t + 6) : na;
            }
            const int q = na > CC ? na - CC : 0;     // exit state in [0,5]
            tbl |= (uint32_t)q << (4 * e);
        }
        tbl_lds[psub][n4 * 4 + c] = tbl;
    }
    __syncthreads();

    // --- Phase 2: publish group map, then lookback-compose predecessors ---
    if (tid < NCH) {
        const int n = tid;

        // Publish this group's entry->exit map (6 nibbles, bit31 clear =
        // valid; payload rides in the same u32 as the flag, no fence needed).
        if (pg < PG - 1) {
            uint32_t gtab = 0;
            #pragma unroll
            for (int e0 = 0; e0 < 6; ++e0) {
                int e = e0;
                #pragma unroll
                for (int s = 0; s < PSUB; ++s)
                    e = (int)((tbl_lds[s][n] >> (4 * e)) & 0xFu);
                gtab |= (uint32_t)e << (4 * e0);
            }
            __hip_atomic_store(msg + (((size_t)b * PG + pg) << 8) + n, gtab,
                               __ATOMIC_RELAXED, __HIP_MEMORY_SCOPE_AGENT);
        }

        // Lookback: compose predecessor maps (all published ~simultaneously).
        int e = 0;
        for (int g = 0; g < pg; ++g) {
            const uint32_t* w = msg + (((size_t)b * PG + g) << 8) + n;
            uint32_t wv;
            while ((wv = __hip_atomic_load(w, __ATOMIC_RELAXED,
                                           __HIP_MEMORY_SCOPE_AGENT)) & 0x80000000u)
                __builtin_amdgcn_s_sleep(1);
            e = (int)((wv >> (4 * e)) & 0xFu);
        }

        // Walk entry state through this block's chunks.
        #pragma unroll
        for (int s = 0; s < PSUB; ++s) {
            ent_lds[s][n] = (uint8_t)e;
            e = (int)((tbl_lds[s][n] >> (4 * e)) & 0xFu);
        }
    }
    __syncthreads();

    // --- Phase 3: emit z from register bits + resolved entry ---
    float4* __restrict__ zv = reinterpret_cast<float4*>(z)
        + ((size_t)b * TT + (size_t)p * CC) * NNV + n4;

    const uint32_t e4 = reinterpret_cast<const uint32_t*>(ent_lds[psub])[n4];
    uint32_t spk[4];
    #pragma unroll
    for (int c = 0; c < 4; ++c) {
        const uint32_t m = cur[c];
        int na = (int)((e4 >> (8 * c)) & 0xFFu);
        uint32_t s = 0;
        #pragma unroll
        for (int it = 0; it < 3; ++it) {
            const uint32_t r = m >> (na & 31);
            const int t = na + __builtin_ctz(r | 0x10000u);
            s |= r ? (1u << (t & 31)) : 0u;   // t < 16 whenever r != 0
            na = r ? (t + 6) : na;
        }
        spk[c] = s;
    }

    #pragma unroll
    for (int j = 0; j < CC; ++j) {
        float4 o;
        o.x = ((spk[0] >> j) & 1u) ? 1.0f : 0.0f;
        o.y = ((spk[1] >> j) & 1u) ? 1.0f : 0.0f;
        o.z = ((spk[2] >> j) & 1u) ? 1.0f : 0.0f;
        o.w = ((spk[3] >> j) & 1u) ? 1.0f : 0.0f;
        zv[(size_t)j * NNV] = o;
    }
}

extern "C" void kernel_launch(void* const* d_in, const int* in_sizes, int n_in,
                              void* d_out, int out_size, void* d_ws, size_t ws_size,
                              hipStream_t stream) {
    const float* x = (const float*)d_in[0];
    float* z = (float*)d_out;
    uint32_t* msg = (uint32_t*)d_ws;

    // Deterministic "not ready" poison (0xAA => bit31 set in every word).
    hipMemsetAsync(d_ws, 0xAA, (size_t)BB * PG * NCH * sizeof(uint32_t), stream);

    refrac_fused<<<dim3(BB * PG), 1024, 0, stream>>>(x, z, msg);
}